// Round 6
// baseline (372.714 us; speedup 1.0000x reference)
//
#include <hip/hip_runtime.h>

// MaskedConv2D bf16-MFMA implicit GEMM, v9. B=8, CIN=COUT=64, H=W=256, K=3, PAD=1.
// GEMM view: M=64 (co), K=576 (ci*9 taps), N=pixels.
//
// v9 vs v8 (post-mortem: occupancy 42->62% gave ZERO BW gain; per-CU tally
// shows HBM duty cycle ~43% because stage->drain->K-loop->epilogue serializes
// and no fetch is in flight during compute). Fix = 2-phase pipeline (guide
// T3-minimum + T14 issue-early/write-late): block persists over 8 y-tiles,
// double-buffered LDS (2 x 26112 B, v8's swizzled layout). Per tile:
//   A: issue next tile's 32 staging loads + 9 mask loads (regs)
//   sched_barrier(0)            // pin loads above compute
//   K-loop on buf[t&1]          // loads fly under ~2000cy of MFMA/ds_read
//   B: vmcnt-drain, f2bf, ds_write buf[(t+1)&1]; valid combine+bpermute
//   one barrier; epilogue stores (overlap next A)
// Consecutive y-tiles share 2 halo rows -> L2-hot refetch -> FETCH drops.
// Grid 8x8x8 = 512 blocks = 2/CU exactly; VGPR target ~105 under (512,4).
//
// mfma_f32_16x16x32_bf16: A[m=lane&15][k=(lane>>4)*8+j], C/D: col=lane&15,
// row=(lane>>4)*4+reg.  Wave w: hrow=w&3, co-half ch=w>>2.

#define B_    8
#define C_    64
#define H_    256
#define W_    256
#define HW_   (H_ * W_)

typedef __attribute__((ext_vector_type(8))) short bf16x8;
typedef __attribute__((ext_vector_type(4))) float f32x4;

__device__ __forceinline__ unsigned short f2bf(float f) {
    unsigned int u = __float_as_uint(f);
    u = (u + 0x7FFFu + ((u >> 16) & 1u)) >> 16;   // RNE
    return (unsigned short)u;
}

// ---- weight conversion: fp32 [co][ci][3][3] -> bf16 A-fragment blob ----
// frag f = s*4 + mf  (s = tap*2 + kblk); lane l holds 8 bf16 at (f*64+l)*16 B:
//   co = mf*16 + (l&15); ci = kblk*32 + (l>>4)*8 + j
__global__ __launch_bounds__(256) void wconv(const float* __restrict__ wgt,
                                             unsigned short* __restrict__ wsA)
{
    const int gid  = blockIdx.x * 256 + threadIdx.x;   // 18*256 = 4608
    const int s    = gid >> 8;
    const int rest = gid & 255;
    const int mf   = rest >> 6;
    const int lane = rest & 63;
    const int tap  = s >> 1;
    const int kblk = s & 1;
    const int kh = tap / 3, kw = tap % 3;
    const int co = mf * 16 + (lane & 15);
    unsigned short v[8];
#pragma unroll
    for (int j = 0; j < 8; ++j) {
        const int ci = kblk * 32 + (lane >> 4) * 8 + j;
        v[j] = f2bf(wgt[((co * C_ + ci) * 3 + kh) * 3 + kw]);
    }
    unsigned short* dst = wsA + (size_t)gid * 8;
    *(uint4*)dst = *(const uint4*)v;
}

// ---- main kernel ----
#define TROWS 6          // 4 + 2 halo
#define TCOLS 34         // 32 + 2 halo
#define NU    (TROWS * TCOLS * 8)   // 1632 staging units
#define NCHUNK 4                    // ceil(1632/512)
#define NTAIL (NU - 3 * 512)        // 96
#define BUFSZ (TROWS * TCOLS * 64)  // shorts per buffer (26112 B)
#define TILES 8                     // y-tiles per block

__global__ __launch_bounds__(512, 4) void masked_conv_mfma(
    const float* __restrict__ x,
    const float* __restrict__ mask,
    const unsigned short* __restrict__ wsA,
    const float* __restrict__ bias,
    float* __restrict__ out)
{
    // two buffers of [cell = row*34+col][8 ci-octets, XOR-swizzled]. 52224 B.
    __shared__ __align__(16) unsigned short xs[2 * BUFSZ];

    const int tid  = threadIdx.x;
    const int wave = tid >> 6;
    const int lane = tid & 63;
    const int l15  = lane & 15;
    const int lq   = lane >> 4;

    const int w0    = blockIdx.x * 32;
    const int hbase = blockIdx.y * (4 * TILES);
    const int b     = blockIdx.z;

    const float* xb = x + (size_t)b * C_ * HW_;
    const float* mb = mask + (size_t)b * HW_;

    const int hrow = wave & 3;        // output row within tile
    const int ch   = wave >> 2;       // co half (0/1)
    const int pcol = w0 + (lane & 31);

    // ---- tile-invariant staging-chunk statics ----
    int ldsoff[NCHUNK], eoff[NCHUNK], rowk[NCHUNK], okwk[NCHUNK];
#pragma unroll
    for (int k = 0; k < NCHUNK; ++k) {
        const int u0 = tid + (k << 9);
        const int u  = (u0 < NU) ? u0 : 0;        // clamp: dup unit 0, write guarded
        const int col = u % TCOLS;
        const int t2  = u / TCOLS;
        const int oct = t2 & 7;
        const int row = t2 >> 3;
        const int gw  = w0 - 1 + col;
        okwk[k] = (gw >= 0) & (gw < W_);
        const int gwc = gw < 0 ? 0 : (gw >= W_ ? W_ - 1 : gw);
        eoff[k] = oct * 8 * HW_ + gwc;            // + ghc*W_ per tile
        const int c = row * TCOLS + col;
        ldsoff[k] = (c << 6) + ((oct ^ (c & 7)) << 3);   // XOR-swizzled slot
        rowk[k] = row;
    }

    float va[NCHUNK][8];
    int   okf[NCHUNK];

    // A: issue staging loads for tile t (branchless clamped addresses)
    auto stage_issue = [&](int t) {
        const int h0 = hbase + 4 * t;
#pragma unroll
        for (int k = 0; k < NCHUNK; ++k) {
            const int gh  = h0 - 1 + rowk[k];
            const int okh = (gh >= 0) & (gh < H_);
            const int ghc = gh < 0 ? 0 : (gh >= H_ ? H_ - 1 : gh);
            okf[k] = okwk[k] & okh;
            const float* px = xb + eoff[k] + (size_t)ghc * W_;
#pragma unroll
            for (int j = 0; j < 8; ++j) va[k][j] = px[(size_t)j * HW_];
        }
    };
    // B: convert + LDS write into buffer bsel
    auto stage_write = [&](int bsel) {
        unsigned short* dst = xs + bsel * BUFSZ;
#pragma unroll
        for (int k = 0; k < NCHUNK; ++k) {
            if (k == NCHUNK - 1 && tid >= NTAIL) continue;
            unsigned short v[8];
#pragma unroll
            for (int j = 0; j < 8; ++j)
                v[j] = okf[k] ? f2bf(va[k][j]) : (unsigned short)0;
            *(uint4*)&dst[ldsoff[k]] = *(const uint4*)v;
        }
    };

    const bf16x8* wA = (const bf16x8*)wsA;

    // ---- prologue: stage tile 0 into buf0 ----
    stage_issue(0);
    stage_write(0);
    __syncthreads();

#pragma unroll 1
    for (int t = 0; t < TILES; ++t) {
        const int h = hbase + 4 * t + hrow;

        // ---- A: issue next tile's staging loads (ride under this K-loop) ----
        if (t + 1 < TILES) stage_issue(t + 1);

        // ---- mask loads for THIS tile: issue now, combine after K ----
        float mv[9];
        int okm = 0;
        {
            int i = 0;
#pragma unroll
            for (int dh = -1; dh <= 1; ++dh) {
#pragma unroll
                for (int dw = -1; dw <= 1; ++dw, ++i) {
                    const int hh = h + dh;
                    const int ww = pcol + dw;
                    const int ok = (hh >= 0) & (hh < H_) & (ww >= 0) & (ww < W_);
                    mv[i] = mb[ok ? (hh * W_ + ww) : 0];
                    okm |= ok << i;
                }
            }
        }
        __builtin_amdgcn_sched_barrier(0);   // pin all loads above the K loop

        // ---- K loop on buf[t&1]: 9 taps x 2 ci-halves, no barriers ----
        const unsigned short* xbuf = xs + (t & 1) * BUFSZ;
        f32x4 acc[2][2];
#pragma unroll
        for (int mf = 0; mf < 2; ++mf)
#pragma unroll
            for (int nf = 0; nf < 2; ++nf)
                acc[mf][nf] = (f32x4){0.f, 0.f, 0.f, 0.f};

#pragma unroll 1
        for (int kh = 0; kh < 3; ++kh) {
            const int rowbase = (hrow + kh) * TCOLS;
#pragma unroll
            for (int kw = 0; kw < 3; ++kw) {
#pragma unroll
                for (int kblk = 0; kblk < 2; ++kblk) {
                    const int s = (kh * 3 + kw) * 2 + kblk;
                    bf16x8 a[2];
#pragma unroll
                    for (int mf = 0; mf < 2; ++mf)
                        a[mf] = wA[(s * 4 + ch * 2 + mf) * 64 + lane];
                    bf16x8 bfv[2];
#pragma unroll
                    for (int nf = 0; nf < 2; ++nf) {
                        const int cell2 = rowbase + nf * 16 + l15 + kw;
                        const int g = kblk * 4 + lq;           // ci-octet group
                        bfv[nf] = *(const bf16x8*)
                            &xbuf[(cell2 << 6) + ((g ^ (cell2 & 7)) << 3)];
                    }
#pragma unroll
                    for (int mf = 0; mf < 2; ++mf)
#pragma unroll
                        for (int nf = 0; nf < 2; ++nf)
                            acc[mf][nf] = __builtin_amdgcn_mfma_f32_16x16x32_bf16(
                                a[mf], bfv[nf], acc[mf][nf], 0, 0, 0);
                }
            }
        }

        // ---- validity combine + bpermutes (mask loads landed long ago) ----
        int valid = 0;
#pragma unroll
        for (int i = 0; i < 9; ++i)
            valid |= ((okm >> i) & 1) & (mv[i] != 0.0f ? 1 : 0);
        const int vn0 = __builtin_amdgcn_ds_bpermute(l15 << 2, valid);
        const int vn1 = __builtin_amdgcn_ds_bpermute((16 + l15) << 2, valid);

        // ---- B: write next tile into the other buffer ----
        if (t + 1 < TILES) stage_write((t + 1) & 1);
        __syncthreads();

        // ---- epilogue: bias + mask select + store (overlaps next A) ----
#pragma unroll
        for (int nf = 0; nf < 2; ++nf) {
            const int cloc = nf * 16 + l15;                   // 0..31 within tile
            const int vn = nf ? vn1 : vn0;
            float* ob = out + ((size_t)(b * C_) * H_ + h) * W_ + w0 + cloc;
#pragma unroll
            for (int mf = 0; mf < 2; ++mf) {
#pragma unroll
                for (int reg = 0; reg < 4; ++reg) {
                    const int co = ch * 32 + mf * 16 + lq * 4 + reg;
                    const float val = vn ? (acc[mf][nf][reg] + bias[co]) : 0.0f;
                    ob[(size_t)co * HW_] = val;
                }
            }
        }
    }
}

extern "C" void kernel_launch(void* const* d_in, const int* in_sizes, int n_in,
                              void* d_out, int out_size, void* d_ws, size_t ws_size,
                              hipStream_t stream) {
    const float* x    = (const float*)d_in[0];
    const float* mask = (const float*)d_in[1];
    const float* wgt  = (const float*)d_in[2];
    const float* bias = (const float*)d_in[3];
    float* out        = (float*)d_out;
    unsigned short* wsA = (unsigned short*)d_ws;   // 73728 B used

    wconv<<<18, 256, 0, stream>>>(wgt, wsA);

    dim3 grid(W_ / 32, H_ / (4 * TILES), B_);   // 8 x 8 x 8 = 512 blocks
    masked_conv_mfma<<<grid, 512, 0, stream>>>(x, mask, wsA, bias, out);
}

// Round 7
// 342.987 us; speedup vs baseline: 1.0867x; 1.0867x over previous
//
#include <hip/hip_runtime.h>

// MaskedConv2D bf16-MFMA implicit GEMM, v10. B=8, CIN=COUT=64, H=W=256, K=3, PAD=1.
// GEMM view: M=64 (co), K=576 (ci*9 taps), N=pixels.
//
// v10 vs v9 (post-mortem: ANY register-staged pipeline gets spilled by the
// allocator when staging data must live across the K-loop; v9: VGPR=64,
// 586MB traffic, occ 4%). Fix: make staging register-free via
// global_load_lds. Blocked before because x is fp32 and MFMA needs bf16 ->
// new pre-pass xconv converts x once: xsw bf16 [b][h][w][64ci] (33.5MB in
// d_ws), with the ds_read XOR swizzle PRE-BAKED into the global layout
// (octet o of pixel (h,w) at slot o^(w&7)); main-kernel staging is then a
// verbatim 16B-granule DMA copy (wave-uniform LDS base + lane*16, rule 21:
// linear LDS dest + pre-swizzled source). Per tile: issue DMA for t+1 ->
// mask loads -> sched_barrier -> K-loop on buf t -> barrier (drains vmcnt;
// loads had the whole K-loop to land) -> epilogue stores. OOB cells: skip
// DMA, ds_write zeros (each granule has exactly ONE writer -> no race).
//
// mfma_f32_16x16x32_bf16: A[m=lane&15][k=(lane>>4)*8+j], C/D: col=lane&15,
// row=(lane>>4)*4+reg.  Wave w: hrow=w&3, co-half ch=w>>2.
// NOTE: requires ws_size >= 73728 + 33554432 bytes.

#define B_    8
#define C_    64
#define H_    256
#define W_    256
#define HW_   (H_ * W_)

typedef __attribute__((ext_vector_type(8))) short bf16x8;
typedef __attribute__((ext_vector_type(4))) float f32x4;

__device__ __forceinline__ unsigned short f2bf(float f) {
    unsigned int u = __float_as_uint(f);
    u = (u + 0x7FFFu + ((u >> 16) & 1u)) >> 16;   // RNE
    return (unsigned short)u;
}

__device__ __forceinline__ void gld_lds16(const void* g, void* l) {
    __builtin_amdgcn_global_load_lds(
        (const __attribute__((address_space(1))) void*)g,
        (__attribute__((address_space(3))) void*)l, 16, 0, 0);
}

// ---- weight conversion: fp32 [co][ci][3][3] -> bf16 A-fragment blob ----
// frag f = s*4 + mf  (s = tap*2 + kblk); lane l holds 8 bf16 at (f*64+l)*16 B:
//   co = mf*16 + (l&15); ci = kblk*32 + (l>>4)*8 + j
__global__ __launch_bounds__(256) void wconv(const float* __restrict__ wgt,
                                             unsigned short* __restrict__ wsA)
{
    const int gid  = blockIdx.x * 256 + threadIdx.x;   // 18*256 = 4608
    const int s    = gid >> 8;
    const int rest = gid & 255;
    const int mf   = rest >> 6;
    const int lane = rest & 63;
    const int tap  = s >> 1;
    const int kblk = s & 1;
    const int kh = tap / 3, kw = tap % 3;
    const int co = mf * 16 + (lane & 15);
    unsigned short v[8];
#pragma unroll
    for (int j = 0; j < 8; ++j) {
        const int ci = kblk * 32 + (lane >> 4) * 8 + j;
        v[j] = f2bf(wgt[((co * C_ + ci) * 3 + kh) * 3 + kw]);
    }
    unsigned short* dst = wsA + (size_t)gid * 8;
    *(uint4*)dst = *(const uint4*)v;
}

// ---- x conversion/transpose: fp32 NCHW -> bf16 [b][h][w][64ci], swizzled ----
// Octet o (ci = 8o..8o+7) of pixel (h,w) stored at 16B slot (o ^ (w&7)).
__global__ __launch_bounds__(256) void xconv(const float* __restrict__ x,
                                             unsigned short* __restrict__ xsw)
{
    const int gid = blockIdx.x * 256 + threadIdx.x;   // 8*65536 -> 2048 blocks exact
    const int b   = gid >> 16;
    const int p   = gid & 65535;                      // h*256+w
    const int gw  = p & 255;
    const float* px = x + (size_t)b * (C_ * HW_) + p;
    unsigned short* dst = xsw + (size_t)gid * 64;
    const int key = gw & 7;
#pragma unroll
    for (int o = 0; o < 8; ++o) {
        unsigned short v[8];
#pragma unroll
        for (int j = 0; j < 8; ++j)
            v[j] = f2bf(px[(size_t)(o * 8 + j) * HW_]);
        *(uint4*)&dst[(o ^ key) << 3] = *(const uint4*)v;
    }
}

// ---- main kernel ----
#define TROWS 6          // 4 + 2 halo
#define TCOLS 34         // 32 + 2 halo
#define NCELL (TROWS * TCOLS)      // 204 cells (pixels) per tile
#define NGRAN (NCELL * 8)          // 1632 16B granules per tile
#define BUFSH (NCELL * 64)         // 13056 shorts = 26112 B per buffer
#define TILES 8                    // y-tiles per block

__global__ __launch_bounds__(512, 4) void masked_conv_mfma(
    const unsigned short* __restrict__ xsw,
    const float* __restrict__ mask,
    const unsigned short* __restrict__ wsA,
    const float* __restrict__ bias,
    float* __restrict__ out)
{
    // two buffers, LINEAR [cell][8 slots x 16B] (swizzle lives in global data)
    __shared__ __align__(16) unsigned short xs[2 * BUFSH];   // 52224 B

    const int tid  = threadIdx.x;
    const int wave = tid >> 6;
    const int lane = tid & 63;
    const int l15  = lane & 15;
    const int lq   = lane >> 4;

    const int w0    = blockIdx.x * 32;
    const int hbase = blockIdx.y * (4 * TILES);
    const int b     = blockIdx.z;

    const int hrow = wave & 3;        // output row within tile
    const int ch   = wave >> 2;       // co half (0/1)
    const int pcol = w0 + (lane & 31);
    const float* mb = mask + (size_t)b * HW_;
    const unsigned short* xbb = xsw + (((size_t)b) << 16) * 64;

    // ---- per-thread staging statics (4 DMA rounds; round r granule = r*512+tid)
    int rowr[4], okwr[4], gcolr[4];
#pragma unroll
    for (int r = 0; r < 4; ++r) {
        const int g  = (r << 9) + tid;
        const int gg = (g < NGRAN) ? g : 0;
        const int cell = gg >> 3, slot = gg & 7;
        rowr[r] = cell / TCOLS;
        const int col = cell % TCOLS;
        const int gw  = w0 - 1 + col;
        okwr[r] = (gw >= 0) & (gw < W_);
        const int gwc = gw < 0 ? 0 : (gw >= W_ ? W_ - 1 : gw);
        gcolr[r] = gwc * 64 + slot * 8;           // shorts within a row-plane
    }

    // stage tile t into buffer bsel: DMA in-bounds granules, zero OOB ones.
    auto stage = [&](int bsel, int t) {
        const int h0 = hbase + (t << 2);
        unsigned short* bufb = xs + bsel * BUFSH;
#pragma unroll
        for (int r = 0; r < 4; ++r) {
            const int g = (r << 9) + tid;
            if (g < NGRAN) {
                const int gh  = h0 - 1 + rowr[r];
                const int okh = (gh >= 0) & (gh < H_);
                if (okh & okwr[r]) {
                    // wave-uniform LDS base; HW adds lane*16
                    unsigned short* ldsb = bufb + (((r << 9) + (wave << 6)) << 3);
                    const unsigned short* gsrc = xbb + (size_t)gh * (W_ * 64) + gcolr[r];
                    gld_lds16(gsrc, ldsb);
                } else {
                    *(uint4*)&bufb[g << 3] = (uint4){0, 0, 0, 0};
                }
            }
        }
    };

    const bf16x8* wA = (const bf16x8*)wsA;

    // ---- prologue: stage tile 0 ----
    stage(0, 0);
    asm volatile("s_waitcnt vmcnt(0)" ::: "memory");
    __syncthreads();

#pragma unroll 1
    for (int t = 0; t < TILES; ++t) {
        const int h = hbase + (t << 2) + hrow;

        // ---- issue next tile's DMA (rides under this K-loop; no registers) ----
        if (t + 1 < TILES) stage((t + 1) & 1, t + 1);

        // ---- mask loads for THIS tile: issue now, combine after K ----
        float mv[9];
        int okm = 0;
        {
            int i = 0;
#pragma unroll
            for (int dh = -1; dh <= 1; ++dh) {
#pragma unroll
                for (int dw = -1; dw <= 1; ++dw, ++i) {
                    const int hh = h + dh;
                    const int ww = pcol + dw;
                    const int ok = (hh >= 0) & (hh < H_) & (ww >= 0) & (ww < W_);
                    mv[i] = mb[ok ? (hh * W_ + ww) : 0];
                    okm |= ok << i;
                }
            }
        }
        __builtin_amdgcn_sched_barrier(0);   // pin all load issues above the K loop

        // ---- K loop on buf[t&1]: 9 taps x 2 ci-halves, no barriers ----
        const unsigned short* xbuf = xs + (t & 1) * BUFSH;
        f32x4 acc[2][2];
#pragma unroll
        for (int mf = 0; mf < 2; ++mf)
#pragma unroll
            for (int nf = 0; nf < 2; ++nf)
                acc[mf][nf] = (f32x4){0.f, 0.f, 0.f, 0.f};

#pragma unroll 1
        for (int kh = 0; kh < 3; ++kh) {
            const int rowbase = (hrow + kh) * TCOLS;
#pragma unroll
            for (int kw = 0; kw < 3; ++kw) {
                const int keyb = (l15 + kw + 7) & 7;     // (gw&7) of this column
#pragma unroll
                for (int kblk = 0; kblk < 2; ++kblk) {
                    const int s = (kh * 3 + kw) * 2 + kblk;
                    bf16x8 a[2];
#pragma unroll
                    for (int mf = 0; mf < 2; ++mf)
                        a[mf] = wA[(s * 4 + ch * 2 + mf) * 64 + lane];
                    bf16x8 bfv[2];
#pragma unroll
                    for (int nf = 0; nf < 2; ++nf) {
                        const int cell2 = rowbase + nf * 16 + l15 + kw;
                        const int g = kblk * 4 + lq;     // ci-octet wanted
                        bfv[nf] = *(const bf16x8*)
                            &xbuf[(cell2 << 6) + ((g ^ keyb) << 3)];
                    }
#pragma unroll
                    for (int mf = 0; mf < 2; ++mf)
#pragma unroll
                        for (int nf = 0; nf < 2; ++nf)
                            acc[mf][nf] = __builtin_amdgcn_mfma_f32_16x16x32_bf16(
                                a[mf], bfv[nf], acc[mf][nf], 0, 0, 0);
                }
            }
        }

        // ---- validity combine + bpermutes (mask loads landed long ago) ----
        int valid = 0;
#pragma unroll
        for (int i = 0; i < 9; ++i)
            valid |= ((okm >> i) & 1) & (mv[i] != 0.0f ? 1 : 0);
        const int vn0 = __builtin_amdgcn_ds_bpermute(l15 << 2, valid);
        const int vn1 = __builtin_amdgcn_ds_bpermute((16 + l15) << 2, valid);

        // ---- barrier: drains vmcnt (t+1 DMA, launched ~full K-loop ago) ----
        __syncthreads();

        // ---- epilogue: bias + mask select + store (overlaps next iter's DMA) ----
#pragma unroll
        for (int nf = 0; nf < 2; ++nf) {
            const int cloc = nf * 16 + l15;               // 0..31 within tile
            const int vn = nf ? vn1 : vn0;
            float* ob = out + ((size_t)(b * C_) * H_ + h) * W_ + w0 + cloc;
#pragma unroll
            for (int mf = 0; mf < 2; ++mf) {
#pragma unroll
                for (int reg = 0; reg < 4; ++reg) {
                    const int co = ch * 32 + mf * 16 + lq * 4 + reg;
                    const float val = vn ? (acc[mf][nf][reg] + bias[co]) : 0.0f;
                    ob[(size_t)co * HW_] = val;
                }
            }
        }
    }
}

extern "C" void kernel_launch(void* const* d_in, const int* in_sizes, int n_in,
                              void* d_out, int out_size, void* d_ws, size_t ws_size,
                              hipStream_t stream) {
    const float* x    = (const float*)d_in[0];
    const float* mask = (const float*)d_in[1];
    const float* wgt  = (const float*)d_in[2];
    const float* bias = (const float*)d_in[3];
    float* out        = (float*)d_out;
    unsigned short* wsA = (unsigned short*)d_ws;                    // 73728 B
    unsigned short* xsw = (unsigned short*)((char*)d_ws + 73728);   // 33.55 MB

    wconv<<<18, 256, 0, stream>>>(wgt, wsA);
    xconv<<<2048, 256, 0, stream>>>(x, xsw);

    dim3 grid(W_ / 32, H_ / (4 * TILES), B_);   // 8 x 8 x 8 = 512 blocks
    masked_conv_mfma<<<grid, 512, 0, stream>>>(xsw, mask, wsA, bias, out);
}

// Round 8
// 319.702 us; speedup vs baseline: 1.1658x; 1.0728x over previous
//
#include <hip/hip_runtime.h>

// MaskedConv2D bf16-MFMA implicit GEMM, v11. B=8, CIN=COUT=64, H=W=256, K=3, PAD=1.
// GEMM view: M=64 (co), K=576 (ci*9 taps), N=pixels.
//
// v11 vs v10 (post-mortem: main kernel dropped out of top-5 (<89us) — the
// global_load_lds DMA pipeline worked. New bottleneck is the xconv pre-pass:
// 90us @ 1.8TB/s, WRITE_SIZE 94MB vs 33.5 ideal (2.8x RMW from 16B-stride-128B
// partial-line stores) + latency-serialized scalar reads (VGPR=32, 64 dword
// loads in shallow rounds). Rewrite: thread owns 4px x 8ci -> 8x float4 loads
// (1KB useful per wave instr, 8x128B segments), register transpose, 4x uint4
// stores where 8 lanes sharing a px-quad write the 8 slots of ONE pixel =
// one full 128B line per store instr (no partial-line RMW). Swizzle layout
// slot = o^(p&7) preserved exactly; main kernel untouched.
//
// mfma_f32_16x16x32_bf16: A[m=lane&15][k=(lane>>4)*8+j], C/D: col=lane&15,
// row=(lane>>4)*4+reg.  Wave w: hrow=w&3, co-half ch=w>>2.
// NOTE: requires ws_size >= 73728 + 33554432 bytes.

#define B_    8
#define C_    64
#define H_    256
#define W_    256
#define HW_   (H_ * W_)

typedef __attribute__((ext_vector_type(8))) short bf16x8;
typedef __attribute__((ext_vector_type(4))) float f32x4;

__device__ __forceinline__ unsigned short f2bf(float f) {
    unsigned int u = __float_as_uint(f);
    u = (u + 0x7FFFu + ((u >> 16) & 1u)) >> 16;   // RNE
    return (unsigned short)u;
}

__device__ __forceinline__ void gld_lds16(const void* g, void* l) {
    __builtin_amdgcn_global_load_lds(
        (const __attribute__((address_space(1))) void*)g,
        (__attribute__((address_space(3))) void*)l, 16, 0, 0);
}

// ---- weight conversion: fp32 [co][ci][3][3] -> bf16 A-fragment blob ----
// frag f = s*4 + mf  (s = tap*2 + kblk); lane l holds 8 bf16 at (f*64+l)*16 B:
//   co = mf*16 + (l&15); ci = kblk*32 + (l>>4)*8 + j
__global__ __launch_bounds__(256) void wconv(const float* __restrict__ wgt,
                                             unsigned short* __restrict__ wsA)
{
    const int gid  = blockIdx.x * 256 + threadIdx.x;   // 18*256 = 4608
    const int s    = gid >> 8;
    const int rest = gid & 255;
    const int mf   = rest >> 6;
    const int lane = rest & 63;
    const int tap  = s >> 1;
    const int kblk = s & 1;
    const int kh = tap / 3, kw = tap % 3;
    const int co = mf * 16 + (lane & 15);
    unsigned short v[8];
#pragma unroll
    for (int j = 0; j < 8; ++j) {
        const int ci = kblk * 32 + (lane >> 4) * 8 + j;
        v[j] = f2bf(wgt[((co * C_ + ci) * 3 + kh) * 3 + kw]);
    }
    unsigned short* dst = wsA + (size_t)gid * 8;
    *(uint4*)dst = *(const uint4*)v;
}

// ---- x conversion/transpose: fp32 NCHW -> bf16 [b][h][w][64ci], swizzled ----
// Octet o (ci = 8o..8o+7) of pixel p=(h,w) stored at 16B slot (o ^ (p&7)).
// Thread = (octet o, px-quad pg): 8x float4 loads (4 px, ci=8o..8o+7),
// register transpose, 4x uint4 stores. Lanes 0..7 of each 8-lane group share
// pg and cover o=0..7 -> store instr i writes the full 128B of pixel 4pg+i.
__global__ __launch_bounds__(256) void xconv(const float* __restrict__ x,
                                             unsigned short* __restrict__ xsw)
{
    const int gid = blockIdx.x * 256 + threadIdx.x;   // 4096 blocks, 1M threads
    const int b   = gid >> 17;                        // 131072 threads per batch
    const int rem = gid & 131071;
    const int o   = rem & 7;
    const int pg  = rem >> 3;                         // px-quad 0..16383
    const int p0  = pg << 2;

    const float* px = x + (size_t)b * (C_ * HW_) + (size_t)(o * 8) * HW_ + p0;
    float4 v[8];
#pragma unroll
    for (int j = 0; j < 8; ++j)
        v[j] = *(const float4*)&px[(size_t)j * HW_];   // ci = 8o+j, px p0..p0+3

    unsigned short* ob = xsw + ((size_t)b * HW_ + p0) * 64;
#pragma unroll
    for (int i = 0; i < 4; ++i) {                      // pixel p0+i
        unsigned short w[8];
        w[0] = f2bf(v[0].x + 0.0f);                    // (use member per i below)
        // transpose: element i of each of the 8 float4s = ci 8o..8o+7 of px p0+i
        const float e0 = (i == 0) ? v[0].x : (i == 1) ? v[0].y : (i == 2) ? v[0].z : v[0].w;
        const float e1 = (i == 0) ? v[1].x : (i == 1) ? v[1].y : (i == 2) ? v[1].z : v[1].w;
        const float e2 = (i == 0) ? v[2].x : (i == 1) ? v[2].y : (i == 2) ? v[2].z : v[2].w;
        const float e3 = (i == 0) ? v[3].x : (i == 1) ? v[3].y : (i == 2) ? v[3].z : v[3].w;
        const float e4 = (i == 0) ? v[4].x : (i == 1) ? v[4].y : (i == 2) ? v[4].z : v[4].w;
        const float e5 = (i == 0) ? v[5].x : (i == 1) ? v[5].y : (i == 2) ? v[5].z : v[5].w;
        const float e6 = (i == 0) ? v[6].x : (i == 1) ? v[6].y : (i == 2) ? v[6].z : v[6].w;
        const float e7 = (i == 0) ? v[7].x : (i == 1) ? v[7].y : (i == 2) ? v[7].z : v[7].w;
        w[0] = f2bf(e0); w[1] = f2bf(e1); w[2] = f2bf(e2); w[3] = f2bf(e3);
        w[4] = f2bf(e4); w[5] = f2bf(e5); w[6] = f2bf(e6); w[7] = f2bf(e7);
        const int slot = o ^ ((p0 + i) & 7);
        *(uint4*)&ob[((size_t)i << 6) + (slot << 3)] = *(const uint4*)w;
    }
}

// ---- main kernel ----
#define TROWS 6          // 4 + 2 halo
#define TCOLS 34         // 32 + 2 halo
#define NCELL (TROWS * TCOLS)      // 204 cells (pixels) per tile
#define NGRAN (NCELL * 8)          // 1632 16B granules per tile
#define BUFSH (NCELL * 64)         // 13056 shorts = 26112 B per buffer
#define TILES 8                    // y-tiles per block

__global__ __launch_bounds__(512, 4) void masked_conv_mfma(
    const unsigned short* __restrict__ xsw,
    const float* __restrict__ mask,
    const unsigned short* __restrict__ wsA,
    const float* __restrict__ bias,
    float* __restrict__ out)
{
    // two buffers, LINEAR [cell][8 slots x 16B] (swizzle lives in global data)
    __shared__ __align__(16) unsigned short xs[2 * BUFSH];   // 52224 B

    const int tid  = threadIdx.x;
    const int wave = tid >> 6;
    const int lane = tid & 63;
    const int l15  = lane & 15;
    const int lq   = lane >> 4;

    const int w0    = blockIdx.x * 32;
    const int hbase = blockIdx.y * (4 * TILES);
    const int b     = blockIdx.z;

    const int hrow = wave & 3;        // output row within tile
    const int ch   = wave >> 2;       // co half (0/1)
    const int pcol = w0 + (lane & 31);
    const float* mb = mask + (size_t)b * HW_;
    const unsigned short* xbb = xsw + (((size_t)b) << 16) * 64;

    // ---- per-thread staging statics (4 DMA rounds; round r granule = r*512+tid)
    int rowr[4], okwr[4], gcolr[4];
#pragma unroll
    for (int r = 0; r < 4; ++r) {
        const int g  = (r << 9) + tid;
        const int gg = (g < NGRAN) ? g : 0;
        const int cell = gg >> 3, slot = gg & 7;
        rowr[r] = cell / TCOLS;
        const int col = cell % TCOLS;
        const int gw  = w0 - 1 + col;
        okwr[r] = (gw >= 0) & (gw < W_);
        const int gwc = gw < 0 ? 0 : (gw >= W_ ? W_ - 1 : gw);
        gcolr[r] = gwc * 64 + slot * 8;           // shorts within a row-plane
    }

    // stage tile t into buffer bsel: DMA in-bounds granules, zero OOB ones.
    auto stage = [&](int bsel, int t) {
        const int h0 = hbase + (t << 2);
        unsigned short* bufb = xs + bsel * BUFSH;
#pragma unroll
        for (int r = 0; r < 4; ++r) {
            const int g = (r << 9) + tid;
            if (g < NGRAN) {
                const int gh  = h0 - 1 + rowr[r];
                const int okh = (gh >= 0) & (gh < H_);
                if (okh & okwr[r]) {
                    // wave-uniform LDS base; HW adds lane*16
                    unsigned short* ldsb = bufb + (((r << 9) + (wave << 6)) << 3);
                    const unsigned short* gsrc = xbb + (size_t)gh * (W_ * 64) + gcolr[r];
                    gld_lds16(gsrc, ldsb);
                } else {
                    *(uint4*)&bufb[g << 3] = (uint4){0, 0, 0, 0};
                }
            }
        }
    };

    const bf16x8* wA = (const bf16x8*)wsA;

    // ---- prologue: stage tile 0 ----
    stage(0, 0);
    asm volatile("s_waitcnt vmcnt(0)" ::: "memory");
    __syncthreads();

#pragma unroll 1
    for (int t = 0; t < TILES; ++t) {
        const int h = hbase + (t << 2) + hrow;

        // ---- issue next tile's DMA (rides under this K-loop; no registers) ----
        if (t + 1 < TILES) stage((t + 1) & 1, t + 1);

        // ---- mask loads for THIS tile: issue now, combine after K ----
        float mv[9];
        int okm = 0;
        {
            int i = 0;
#pragma unroll
            for (int dh = -1; dh <= 1; ++dh) {
#pragma unroll
                for (int dw = -1; dw <= 1; ++dw, ++i) {
                    const int hh = h + dh;
                    const int ww = pcol + dw;
                    const int ok = (hh >= 0) & (hh < H_) & (ww >= 0) & (ww < W_);
                    mv[i] = mb[ok ? (hh * W_ + ww) : 0];
                    okm |= ok << i;
                }
            }
        }
        __builtin_amdgcn_sched_barrier(0);   // pin all load issues above the K loop

        // ---- K loop on buf[t&1]: 9 taps x 2 ci-halves, no barriers ----
        const unsigned short* xbuf = xs + (t & 1) * BUFSH;
        f32x4 acc[2][2];
#pragma unroll
        for (int mf = 0; mf < 2; ++mf)
#pragma unroll
            for (int nf = 0; nf < 2; ++nf)
                acc[mf][nf] = (f32x4){0.f, 0.f, 0.f, 0.f};

#pragma unroll 1
        for (int kh = 0; kh < 3; ++kh) {
            const int rowbase = (hrow + kh) * TCOLS;
#pragma unroll
            for (int kw = 0; kw < 3; ++kw) {
                const int keyb = (l15 + kw + 7) & 7;     // (gw&7) of this column
#pragma unroll
                for (int kblk = 0; kblk < 2; ++kblk) {
                    const int s = (kh * 3 + kw) * 2 + kblk;
                    bf16x8 a[2];
#pragma unroll
                    for (int mf = 0; mf < 2; ++mf)
                        a[mf] = wA[(s * 4 + ch * 2 + mf) * 64 + lane];
                    bf16x8 bfv[2];
#pragma unroll
                    for (int nf = 0; nf < 2; ++nf) {
                        const int cell2 = rowbase + nf * 16 + l15 + kw;
                        const int g = kblk * 4 + lq;     // ci-octet wanted
                        bfv[nf] = *(const bf16x8*)
                            &xbuf[(cell2 << 6) + ((g ^ keyb) << 3)];
                    }
#pragma unroll
                    for (int mf = 0; mf < 2; ++mf)
#pragma unroll
                        for (int nf = 0; nf < 2; ++nf)
                            acc[mf][nf] = __builtin_amdgcn_mfma_f32_16x16x32_bf16(
                                a[mf], bfv[nf], acc[mf][nf], 0, 0, 0);
                }
            }
        }

        // ---- validity combine + bpermutes (mask loads landed long ago) ----
        int valid = 0;
#pragma unroll
        for (int i = 0; i < 9; ++i)
            valid |= ((okm >> i) & 1) & (mv[i] != 0.0f ? 1 : 0);
        const int vn0 = __builtin_amdgcn_ds_bpermute(l15 << 2, valid);
        const int vn1 = __builtin_amdgcn_ds_bpermute((16 + l15) << 2, valid);

        // ---- barrier: drains vmcnt (t+1 DMA, launched ~full K-loop ago) ----
        __syncthreads();

        // ---- epilogue: bias + mask select + store (overlaps next iter's DMA) ----
#pragma unroll
        for (int nf = 0; nf < 2; ++nf) {
            const int cloc = nf * 16 + l15;               // 0..31 within tile
            const int vn = nf ? vn1 : vn0;
            float* ob = out + ((size_t)(b * C_) * H_ + h) * W_ + w0 + cloc;
#pragma unroll
            for (int mf = 0; mf < 2; ++mf) {
#pragma unroll
                for (int reg = 0; reg < 4; ++reg) {
                    const int co = ch * 32 + mf * 16 + lq * 4 + reg;
                    const float val = vn ? (acc[mf][nf][reg] + bias[co]) : 0.0f;
                    ob[(size_t)co * HW_] = val;
                }
            }
        }
    }
}

extern "C" void kernel_launch(void* const* d_in, const int* in_sizes, int n_in,
                              void* d_out, int out_size, void* d_ws, size_t ws_size,
                              hipStream_t stream) {
    const float* x    = (const float*)d_in[0];
    const float* mask = (const float*)d_in[1];
    const float* wgt  = (const float*)d_in[2];
    const float* bias = (const float*)d_in[3];
    float* out        = (float*)d_out;
    unsigned short* wsA = (unsigned short*)d_ws;                    // 73728 B
    unsigned short* xsw = (unsigned short*)((char*)d_ws + 73728);   // 33.55 MB

    wconv<<<18, 256, 0, stream>>>(wgt, wsA);
    xconv<<<4096, 256, 0, stream>>>(x, xsw);

    dim3 grid(W_ / 32, H_ / (4 * TILES), B_);   // 8 x 8 x 8 = 512 blocks
    masked_conv_mfma<<<grid, 512, 0, stream>>>(xsw, mask, wsA, bias, out);
}